// Round 9
// baseline (134.378 us; speedup 1.0000x reference)
//
#include <hip/hip_runtime.h>

// Photoreceptor Rieke model: 40,000 independent nonlinear ODE chains,
// sequential over T=1000, coalesced over p.
// R9 = R8 with the phase-coverage bug fixed (R8's loop covered phases 1..120
// then jumped to 123 -> chunks 121/122 never computed, absmax=40 = dark
// current). Design unchanged:
//  - R7's DMA skeleton: global_load_lds triple-buffer, counted vmcnt waits,
//    1 wave/block, no barriers, zero register buffers.
//  - bulk LDS->reg read per phase behind ONE lgkmcnt(0) (R7 paid ds_read
//    latency per step).
//  - ILP=2 chains/thread (b and b+8): B's ops fill A's dep stalls.
#define B_ 16
#define T_ 1000
#define P_ 2500
#define HALF 20000                  // threads; chain A=tid, chain B=tid+20000

#define AS1 __attribute__((address_space(1)))
#define AS3 __attribute__((address_space(3)))

__device__ __forceinline__ float rcp_fast(float v) {
    return __builtin_amdgcn_rcpf(v);   // ~1 ulp, single v_rcp_f32
}

extern "C" __global__ void __launch_bounds__(64, 1)
prk_kernel(const float* __restrict__ x,
           const float* __restrict__ sigma_p,  const float* __restrict__ phi_p,
           const float* __restrict__ eta_p,    const float* __restrict__ c2c_p,
           const float* __restrict__ hill_p,   const float* __restrict__ cdark_p,
           const float* __restrict__ beta_p,   const float* __restrict__ bslow_p,
           const float* __restrict__ hcoef_p,  const float* __restrict__ haff_p,
           const float* __restrict__ gamma_p,  const float* __restrict__ gdark_p,
           float* __restrict__ out)
{
    const int lane = threadIdx.x;
    const int tid  = blockIdx.x * 64 + lane;
    if (tid >= HALF) return;                 // lanes 32..63 of block 312
    const int b = tid / P_;                  // 0..7
    const int p = tid - b * P_;

    const float sigma        = sigma_p[0];
    const float phi          = phi_p[0];
    const float eta          = eta_p[0];
    const float cgmp2cur     = c2c_p[0];
    const float cgmphill     = hill_p[0];
    const float cdark        = cdark_p[0];
    const float beta         = beta_p[0];
    const float betaSlow     = bslow_p[0];
    const float hillcoef     = hcoef_p[0];
    const float hillaffinity = haff_p[0];
    const float gamma        = gamma_p[0] * 0.125f;  // gamma / timeBin(8)
    const float gdark        = gdark_p[0];
    const float DT = 0.008f;                          // 0.001 * 8

    // derived constants (uniform -> SGPRs)
    const float darkCurrent = powf(gdark, cgmphill) * cgmp2cur * 0.5f;
    const float gdark_ = powf(2.0f * darkCurrent / cgmp2cur, 1.0f / cgmphill);
    const float cur2ca = beta * cdark / darkCurrent;
    const float smax   = eta / phi * gdark_ *
                         (1.0f + powf(cdark / hillaffinity, hillcoef));

    const float Ar  = 1.0f - DT * sigma;
    const float Ap  = 1.0f - DT * phi;
    const float Pe  = DT * eta;
    const float Ac  = 1.0f - DT * beta;
    const float Kc  = DT * cur2ca * cgmp2cur;
    const float Acs = 1.0f - DT * betaSlow;
    const float Bcs = DT * betaSlow;
    const float inv_cd = 1.0f / cdark;
    const float inv_ha = 1.0f / hillaffinity;
    const float outk   = -0.5f * cgmp2cur;

    const size_t halfStride = (size_t)8 * T_ * P_;
    const float* __restrict__ xA = x   + (size_t)b * T_ * P_ + p;
    const float* __restrict__ xB = xA  + halfStride;
    float*       __restrict__ oA = out + (size_t)b * T_ * P_ + p;
    float*       __restrict__ oB = oA  + halfStride;

    // per-chain state; g3 = g^3 carried (out = outk * g3_next)
    struct St { float r, pv, c, cs, s, g, g3; };
    auto initSt = [&](float x0) {
        St S;
        S.r  = x0 * gamma / sigma;
        S.pv = (eta + S.r) / phi;
        S.g  = gdark_;
        S.g3 = gdark_ * gdark_ * gdark_;
        S.s  = gdark_ * eta / phi;
        S.c  = cdark;
        S.cs = cdark;
        return S;
    };
    St SA = initSt(xA[0]), SB = initSt(xB[0]);
    oA[0] = 0.0f; oB[0] = 0.0f;

    if (cgmphill == 3.0f && hillcoef == 4.0f) {
        auto step = [&](St& S, float xt) -> float {
            float r1  = fmaf(Ar, S.r, gamma * xt);
            float p1  = fmaf(Ap, S.pv, fmaf(DT, S.r, Pe));
            float den = fmaf(S.cs, inv_cd, 1.0f);
            float c1  = fmaf(Ac, S.c, Kc * S.g3 * rcp_fast(den));
            float cs1 = fmaf(Acs, S.cs, Bcs * S.c);
            float yy  = c1 * inv_ha;
            float y2  = yy * yy;
            float s1  = smax * rcp_fast(fmaf(y2, y2, 1.0f));
            float g1  = fmaf(DT, fmaf(-S.pv, S.g, S.s), S.g);
            float g1c = (g1 * g1) * g1;
            S.r = r1; S.pv = p1; S.c = c1; S.cs = cs1; S.s = s1;
            S.g = g1; S.g3 = g1c;
            return outk * g1c;
        };

        // 3 bufs x 8 rows x 2 chains x 64 lanes = 12 KB
        __shared__ float xlds[3][8][2][64];
        float vxA[8], vxB[8];

#define WAITV(n) do {                                                    \
            asm volatile("s_waitcnt vmcnt(" #n ")" ::: "memory");        \
            __builtin_amdgcn_sched_barrier(0);                           \
        } while (0)
// stage chunk ck (rows 8ck..8ck+7, clamped at 998): 16 DMA ops, zero VGPRs
#define STAGE(ck) do {                                                   \
            const int _bi = (ck) % 3;                                    \
            _Pragma("unroll")                                            \
            for (int _u = 0; _u < 8; ++_u) {                             \
                int _tt = 8 * (ck) + _u;                                 \
                _tt = _tt > 998 ? 998 : _tt;                             \
                __builtin_amdgcn_global_load_lds(                        \
                    (const AS1 void*)(const void*)(xA + (size_t)_tt * P_), \
                    (AS3 void*)(void*)&xlds[_bi][_u][0][0], 4, 0, 0);    \
                __builtin_amdgcn_global_load_lds(                        \
                    (const AS1 void*)(const void*)(xB + (size_t)_tt * P_), \
                    (AS3 void*)(void*)&xlds[_bi][_u][1][0], 4, 0, 0);    \
            }                                                            \
        } while (0)
// bulk LDS->reg: 16 ds_read, ONE lgkmcnt(0), fenced so they can't sink
#define READC(ck) do {                                                   \
            const int _bi = (ck) % 3;                                    \
            _Pragma("unroll")                                            \
            for (int _u = 0; _u < 8; ++_u) {                             \
                vxA[_u] = xlds[_bi][_u][0][lane];                        \
                vxB[_u] = xlds[_bi][_u][1][lane];                        \
            }                                                            \
            asm volatile("s_waitcnt lgkmcnt(0)" ::: "memory");           \
            __builtin_amdgcn_sched_barrier(0);                           \
        } while (0)
// compute nst step-pairs of chunk ck (A and B interleave in the scheduler)
#define COMP(ck, nst) do {                                               \
            _Pragma("unroll")                                            \
            for (int _u = 0; _u < (nst); ++_u) {                         \
                const size_t _t1 = (size_t)(8 * (ck) + _u + 1);          \
                float _vA = step(SA, vxA[_u]);                           \
                float _vB = step(SB, vxB[_u]);                           \
                __builtin_nontemporal_store(_vA, oA + _t1 * P_);         \
                __builtin_nontemporal_store(_vB, oB + _t1 * P_);         \
            }                                                            \
        } while (0)

        // ---- phase coverage: 0 | 1..120 (loop) | 121 | 122 | 123 | 124 ----
        // prologue: chunks 0,1 in flight (32 DMA outstanding)
        STAGE(0); STAGE(1);
        // phase 0: younger-than-L0 = L1 (16)
        WAITV(16); READC(0); STAGE(2); COMP(0, 8);
        // phases 1..120: younger-than-L(k) = S(k-2)+L(k+1)+S(k-1) = 48;
        // vmcnt(32) with in-order retirement proves L(k) landed.
        #pragma unroll 1
        for (int kk = 1; kk <= 118; kk += 3) {
            WAITV(32); READC(kk    ); STAGE(kk + 2); COMP(kk,     8);
            WAITV(32); READC(kk + 1); STAGE(kk + 3); COMP(kk + 1, 8);
            WAITV(32); READC(kk + 2); STAGE(kk + 4); COMP(kk + 2, 8);
        }
        // phases 121, 122 (R8 skipped these -> absmax 40)
        WAITV(32); READC(121); STAGE(123); COMP(121, 8);
        WAITV(32); READC(122); STAGE(124); COMP(122, 8);
        // phase 123: younger-than-L123 = S(121)+L(124)+S(122) = 48
        WAITV(32); READC(123); COMP(123, 8);
        // phase 124: younger-than-L124 = S(122)+S(123) = 32
        WAITV(32); READC(124); COMP(124, 7);   // t = 992..998

#undef WAITV
#undef STAGE
#undef READC
#undef COMP
    } else {
        // ---- generic fallback (exact powf; never taken for bench params) ----
        const float* xs[2] = { xA, xB };
        float*       os[2] = { oA, oB };
        St           ss[2] = { SA, SB };
        for (int k = 0; k < 2; ++k) {
            St S = ss[k];
            for (int t = 0; t < T_ - 1; ++t) {
                float xt  = xs[k][(size_t)t * P_];
                float r1  = S.r + DT * (-sigma * S.r) + gamma * xt;
                float p1  = S.pv + DT * (S.r + eta - phi * S.pv);
                float c1  = S.c + DT * (cur2ca * cgmp2cur * powf(S.g, cgmphill) /
                                        (1.0f + S.cs / cdark) - beta * S.c);
                float cs1 = S.cs - DT * (betaSlow * (S.cs - S.c));
                float s1  = smax / (1.0f + powf(c1 / hillaffinity, hillcoef));
                float g1  = S.g + DT * (S.s - S.pv * S.g);
                os[k][(size_t)(t + 1) * P_] =
                    -(cgmp2cur * powf(g1, cgmphill)) * 0.5f;
                S.r = r1; S.pv = p1; S.c = c1; S.cs = cs1; S.s = s1; S.g = g1;
            }
        }
    }
}

extern "C" void kernel_launch(void* const* d_in, const int* in_sizes, int n_in,
                              void* d_out, int out_size, void* d_ws, size_t ws_size,
                              hipStream_t stream) {
    const float* x = (const float*)d_in[0];
    prk_kernel<<<dim3((HALF + 63) / 64), dim3(64), 0, stream>>>(
        x,
        (const float*)d_in[1],  (const float*)d_in[2],  (const float*)d_in[3],
        (const float*)d_in[4],  (const float*)d_in[5],  (const float*)d_in[6],
        (const float*)d_in[7],  (const float*)d_in[8],  (const float*)d_in[9],
        (const float*)d_in[10], (const float*)d_in[11], (const float*)d_in[12],
        (float*)d_out);
}

// Round 10
// 81.292 us; speedup vs baseline: 1.6530x; 1.6530x over previous
//
#include <hip/hip_runtime.h>

// Photoreceptor Rieke model: 40,000 independent nonlinear ODE chains,
// sequential over T=1000, coalesced over p.
// R10: producer/consumer wave split. 2 waves/block:
//   wave0 (compute): 64 chains, DMA x-staging (global_load_lds, 3-buf,
//     counted WAITV(16) -- queue holds ONLY loads now), results -> LDS obuf.
//   wave1 (writer): flushes obuf chunks as NT dwordx4 stores.
// Sync: raw s_barrier (NO vmcnt drain) + manual lgkmcnt(0) -- m201 pattern.
// Rationale: R3/R5/R7 all converge at ~73us (load path exonerated); R9
// showed per-wave time scales with the wave's own vmem ops (stores in the
// in-order vmcnt queue poison every load-wait) and TLP is 0.61 waves/SIMD.
// This removes stores from compute waves AND doubles TLP to 1250 waves.
#define B_ 16
#define T_ 1000
#define P_ 2500
#define NCH (B_ * P_)   // 40000 = 625 blocks * 64 chains exactly

#define AS1 __attribute__((address_space(1)))
#define AS3 __attribute__((address_space(3)))
typedef float f4 __attribute__((ext_vector_type(4)));

__device__ __forceinline__ float rcp_fast(float v) {
    return __builtin_amdgcn_rcpf(v);   // ~1 ulp, single v_rcp_f32
}

extern "C" __global__ void __launch_bounds__(128, 1)
prk_kernel(const float* __restrict__ x,
           const float* __restrict__ sigma_p,  const float* __restrict__ phi_p,
           const float* __restrict__ eta_p,    const float* __restrict__ c2c_p,
           const float* __restrict__ hill_p,   const float* __restrict__ cdark_p,
           const float* __restrict__ beta_p,   const float* __restrict__ bslow_p,
           const float* __restrict__ hcoef_p,  const float* __restrict__ haff_p,
           const float* __restrict__ gamma_p,  const float* __restrict__ gdark_p,
           float* __restrict__ out)
{
    const int lane = threadIdx.x & 63;
    const int wv   = threadIdx.x >> 6;           // 0 = compute, 1 = writer

    const float sigma        = sigma_p[0];
    const float phi          = phi_p[0];
    const float eta          = eta_p[0];
    const float cgmp2cur     = c2c_p[0];
    const float cgmphill     = hill_p[0];
    const float cdark        = cdark_p[0];
    const float beta         = beta_p[0];
    const float betaSlow     = bslow_p[0];
    const float hillcoef     = hcoef_p[0];
    const float hillaffinity = haff_p[0];
    const float gamma        = gamma_p[0] * 0.125f;  // gamma / timeBin(8)
    const float gdark        = gdark_p[0];
    const float DT = 0.008f;                          // 0.001 * 8

    // derived constants (uniform -> SGPRs)
    const float darkCurrent = powf(gdark, cgmphill) * cgmp2cur * 0.5f;
    const float gdark_ = powf(2.0f * darkCurrent / cgmp2cur, 1.0f / cgmphill);
    const float cur2ca = beta * cdark / darkCurrent;
    const float smax   = eta / phi * gdark_ *
                         (1.0f + powf(cdark / hillaffinity, hillcoef));

    const float Ar  = 1.0f - DT * sigma;
    const float Ap  = 1.0f - DT * phi;
    const float Pe  = DT * eta;
    const float Ac  = 1.0f - DT * beta;
    const float Kc  = DT * cur2ca * cgmp2cur;
    const float Acs = 1.0f - DT * betaSlow;
    const float Bcs = DT * betaSlow;
    const float inv_cd = 1.0f / cdark;
    const float inv_ha = 1.0f / hillaffinity;
    const float outk   = -0.5f * cgmp2cur;

    // compute-wave chain mapping (1 lane = 1 chain)
    const int cid = blockIdx.x * 64 + lane;
    const int b   = cid / P_;
    const int p   = cid - b * P_;
    const float* __restrict__ xrow = x   + (size_t)b * T_ * P_ + p;
    float*       __restrict__ oprt = out + (size_t)b * T_ * P_ + p;

    // writer-wave quad mapping (1 lane moves float4 of 4 chains; P%4==0 so
    // a quad never straddles a batch boundary)
    const int colg = (lane & 15) * 4;
    const int rowl = lane >> 4;
    const int cidL = blockIdx.x * 64 + colg;
    const int b_l  = cidL / P_;
    const int p_l  = cidL - b_l * P_;
    float* __restrict__ old_ = out + (size_t)b_l * T_ * P_ + p_l;

    __shared__ float xlds[3][16][64];    // 12 KB x-staging ring
    __shared__ float obuf[2][16][64];    //  8 KB output ring

    if (cgmphill == 3.0f && hillcoef == 4.0f) {

#define SYNC() do {                                                      \
            asm volatile("s_waitcnt lgkmcnt(0)" ::: "memory");           \
            __builtin_amdgcn_sched_barrier(0);                           \
            __builtin_amdgcn_s_barrier();                                \
            __builtin_amdgcn_sched_barrier(0);                           \
        } while (0)

        if (wv == 0) {
            // ---------------- compute wave ----------------
            float r  = xrow[0] * gamma / sigma;
            float pv = (eta + r) / phi;
            float g  = gdark_;
            float g3 = gdark_ * gdark_ * gdark_;
            float s  = gdark_ * eta / phi;
            float c  = cdark;
            float cs = cdark;
            float vx[16];

#define WAITV(n) do {                                                    \
            asm volatile("s_waitcnt vmcnt(" #n ")" ::: "memory");        \
            __builtin_amdgcn_sched_barrier(0);                           \
        } while (0)
#define STAGE(ck) do {                                                   \
            float* _dst = &xlds[(ck) % 3][0][0];                         \
            _Pragma("unroll")                                            \
            for (int _u = 0; _u < 16; ++_u) {                            \
                int _tt = 16 * (ck) + _u;                                \
                _tt = _tt > 998 ? 998 : _tt;                             \
                __builtin_amdgcn_global_load_lds(                        \
                    (const AS1 void*)(const void*)(xrow + (size_t)_tt * P_), \
                    (AS3 void*)(void*)(_dst + _u * 64), 4, 0, 0);        \
            }                                                            \
        } while (0)
#define READC(bi) do {                                                   \
            _Pragma("unroll")                                            \
            for (int _u = 0; _u < 16; ++_u)                              \
                vx[_u] = xlds[bi][_u][lane];                             \
            asm volatile("s_waitcnt lgkmcnt(0)" ::: "memory");           \
            __builtin_amdgcn_sched_barrier(0);                           \
        } while (0)
#define COMP(ob, nst) do {                                               \
            _Pragma("unroll")                                            \
            for (int _u = 0; _u < (nst); ++_u) {                         \
                float xt  = vx[_u];                                      \
                float r1  = fmaf(Ar, r, gamma * xt);                     \
                float p1  = fmaf(Ap, pv, fmaf(DT, r, Pe));               \
                float den = fmaf(cs, inv_cd, 1.0f);                      \
                float c1  = fmaf(Ac, c, Kc * g3 * rcp_fast(den));        \
                float cs1 = fmaf(Acs, cs, Bcs * c);                      \
                float yy  = c1 * inv_ha;                                 \
                float y2  = yy * yy;                                     \
                float s1  = smax * rcp_fast(fmaf(y2, y2, 1.0f));         \
                float g1  = fmaf(DT, fmaf(-pv, g, s), g);                \
                float g1c = (g1 * g1) * g1;                              \
                obuf[ob][_u][lane] = outk * g1c;                         \
                r = r1; pv = p1; c = c1; cs = cs1; s = s1;               \
                g = g1; g3 = g1c;                                        \
            }                                                            \
        } while (0)

            STAGE(0); STAGE(1);
            int bi = 0, ob = 0;
            #pragma unroll 1
            for (int k = 0; k <= 60; ++k) {
                WAITV(16);                  // L(k) retired; L(k+1) in flight
                READC(bi);
                COMP(ob, 16);
                STAGE(k + 2);
                SYNC();
                bi = (bi == 2) ? 0 : bi + 1;
                ob ^= 1;
            }
            // phase 61: L(62) may stay in flight
            WAITV(16); READC(bi); COMP(ob, 16); SYNC();
            bi = (bi == 2) ? 0 : bi + 1;  ob ^= 1;
            // phase 62: only L(62) in queue -> must drain fully
            WAITV(0);  READC(bi); COMP(ob, 7);  SYNC();
            // writer does the final flush after this barrier; we exit.
#undef WAITV
#undef STAGE
#undef READC
#undef COMP
        } else {
            // ---------------- writer wave ----------------
#define FLUSH(ck, ob, nrow) do {                                         \
            _Pragma("unroll")                                            \
            for (int _i = 0; _i < 4; ++_i) {                             \
                const int _rr = rowl + 4 * _i;                           \
                if (_rr < (nrow)) {                                      \
                    f4 _v = *(const f4*)&obuf[ob][_rr][colg];            \
                    __builtin_nontemporal_store(_v,                      \
                        (f4*)(old_ + (size_t)(16 * (ck) + 1 + _rr) * P_)); \
                }                                                        \
            }                                                            \
        } while (0)
            // phase 0: out row 0 = 0 for this block's 64 chains
            if (lane < 16) {
                f4 z = {0.0f, 0.0f, 0.0f, 0.0f};
                __builtin_nontemporal_store(z, (f4*)old_);
            }
            SYNC();
            int ob = 0;
            #pragma unroll 1
            for (int k = 1; k <= 62; ++k) {      // flush chunk k-1
                FLUSH(k - 1, ob, 16);
                SYNC();
                ob ^= 1;
            }
            FLUSH(62, ob, 7);                    // rows 993..999
#undef FLUSH
        }
#undef SYNC
    } else {
        // ---- generic fallback (exact powf; never taken for bench params) ----
        if (wv != 0) return;
        float r  = xrow[0] * gamma / sigma;
        float pv = (eta + r) / phi;
        float g  = gdark_;
        float s  = gdark_ * eta / phi;
        float c  = cdark;
        float cs = cdark;
        oprt[0] = 0.0f;
        for (int t = 0; t < T_ - 1; ++t) {
            float xt  = xrow[(size_t)t * P_];
            float r1  = r + DT * (-sigma * r) + gamma * xt;
            float p1  = pv + DT * (r + eta - phi * pv);
            float c1  = c + DT * (cur2ca * cgmp2cur * powf(g, cgmphill) /
                                  (1.0f + cs / cdark) - beta * c);
            float cs1 = cs - DT * (betaSlow * (cs - c));
            float s1  = smax / (1.0f + powf(c1 / hillaffinity, hillcoef));
            float g1  = g + DT * (s - pv * g);
            oprt[(size_t)(t + 1) * P_] = -(cgmp2cur * powf(g1, cgmphill)) * 0.5f;
            r = r1; pv = p1; c = c1; cs = cs1; s = s1; g = g1;
        }
    }
}

extern "C" void kernel_launch(void* const* d_in, const int* in_sizes, int n_in,
                              void* d_out, int out_size, void* d_ws, size_t ws_size,
                              hipStream_t stream) {
    const float* x = (const float*)d_in[0];
    prk_kernel<<<dim3(NCH / 64), dim3(128), 0, stream>>>(
        x,
        (const float*)d_in[1],  (const float*)d_in[2],  (const float*)d_in[3],
        (const float*)d_in[4],  (const float*)d_in[5],  (const float*)d_in[6],
        (const float*)d_in[7],  (const float*)d_in[8],  (const float*)d_in[9],
        (const float*)d_in[10], (const float*)d_in[11], (const float*)d_in[12],
        (float*)d_out);
}